// Round 1
// baseline (912.370 us; speedup 1.0000x reference)
//
#include <hip/hip_runtime.h>
#include <hip/hip_bf16.h>

// ---------------- problem constants ----------------
constexpr int T  = 16384;   // B*S tokens
constexpr int Dh = 768;
constexpr int Fh = 3072;
constexpr int Eh = 8;
constexpr int MAXT = 128;   // max 128-row tiles per expert (covers count==T)

typedef unsigned short ushort_t;
typedef __attribute__((ext_vector_type(8))) short  bf16x8;  // 8 bf16 = 4 VGPRs
typedef __attribute__((ext_vector_type(4))) float  f32x4;

// fp32 -> bf16 round-to-nearest-even (finite inputs)
static __device__ __forceinline__ ushort_t f2bf(float f) {
    unsigned u = __builtin_bit_cast(unsigned, f);
    u += 0x7FFFu + ((u >> 16) & 1u);
    return (ushort_t)(u >> 16);
}

// ---------------- init: zero the expert counters ----------------
__global__ void init_counts(int* counts) {
    if (threadIdx.x < Eh) counts[threadIdx.x] = 0;
}

// ---------------- router: one wave per token ----------------
// fp64 accumulation so argmax matches the reference bit-for-bit in practice.
__global__ void router_kernel(const float* __restrict__ x, const float* __restrict__ rw,
                              float* __restrict__ logits_out, float* __restrict__ eidx_out,
                              float* __restrict__ topp, int* __restrict__ counts,
                              int* __restrict__ perm) {
    int gt   = blockIdx.x * 256 + threadIdx.x;
    int t    = gt >> 6;
    int lane = threadIdx.x & 63;
    const float* xr = x + (size_t)t * Dh;

    double acc[Eh];
#pragma unroll
    for (int e = 0; e < Eh; ++e) acc[e] = 0.0;

#pragma unroll
    for (int j = 0; j < Dh / 64; ++j) {
        int d = lane + j * 64;
        float xv = xr[d];
        const float* rwr = rw + d * Eh;
#pragma unroll
        for (int e = 0; e < Eh; ++e) acc[e] += (double)xv * (double)rwr[e];
    }
#pragma unroll
    for (int off = 32; off > 0; off >>= 1) {
#pragma unroll
        for (int e = 0; e < Eh; ++e) acc[e] += __shfl_xor(acc[e], off, 64);
    }
    if (lane == 0) {
        float l32[Eh];
        float m = -3.4e38f; int amax = 0;
#pragma unroll
        for (int e = 0; e < Eh; ++e) l32[e] = (float)acc[e];
#pragma unroll
        for (int e = 0; e < Eh; ++e) {
            if (l32[e] > m) { m = l32[e]; amax = e; }  // strict > : first max wins (np.argmax)
        }
        float s = 0.f;
#pragma unroll
        for (int e = 0; e < Eh; ++e) s += expf(l32[e] - m);
#pragma unroll
        for (int e = 0; e < Eh; ++e) logits_out[(size_t)t * Eh + e] = l32[e];
        eidx_out[t] = (float)amax;
        topp[t]     = 1.0f / s;   // softmax prob of the max logit
        int slot = atomicAdd(&counts[amax], 1);
        perm[amax * T + slot] = t;
    }
}

// ---------------- exclusive scan of 8 counts ----------------
__global__ void scan_counts(const int* counts, int* offsets) {
    if (threadIdx.x == 0) {
        int off = 0;
        for (int e = 0; e < Eh; ++e) { offsets[e] = off; off += counts[e]; }
        offsets[Eh] = off;
    }
}

// ---------------- gather tokens into expert-sorted bf16 rows ----------------
__global__ void gather_cast_x(const float* __restrict__ x, const int* __restrict__ offsets,
                              const int* __restrict__ perm, ushort_t* __restrict__ Xg) {
    __shared__ int soff[Eh + 1];
    if (threadIdx.x < Eh + 1) soff[threadIdx.x] = offsets[threadIdx.x];
    __syncthreads();
    int q  = blockIdx.x * 256 + threadIdx.x;     // float4 index, exact grid
    int g  = q / (Dh / 4);
    int cq = (q - g * (Dh / 4)) * 4;
    int e = 0;
#pragma unroll
    for (int i = 1; i < Eh; ++i) e += (g >= soff[i]);
    int tok = perm[e * T + (g - soff[e])];
    const float4 v = *(const float4*)(x + (size_t)tok * Dh + cq);
    ushort4 o;
    o.x = f2bf(v.x); o.y = f2bf(v.y); o.z = f2bf(v.z); o.w = f2bf(v.w);
    *(ushort4*)(Xg + (size_t)g * Dh + cq) = o;
}

// ---------------- transpose + cast weights: src[R][C] fp32 -> dst[C][R] bf16 ----------------
__global__ void transpose_cvt(const float* __restrict__ src, ushort_t* __restrict__ dst,
                              int R, int C) {
    __shared__ ushort_t tile[32][33];
    int tx = threadIdx.x, ty = threadIdx.y;      // block (32, 8)
    size_t base = (size_t)blockIdx.z * (size_t)R * (size_t)C;
    int c0 = blockIdx.x * 32, r0 = blockIdx.y * 32;
#pragma unroll
    for (int j = 0; j < 4; ++j) {
        int r = ty + j * 8;
        tile[r][tx] = f2bf(src[base + (size_t)(r0 + r) * C + c0 + tx]);
    }
    __syncthreads();
#pragma unroll
    for (int j = 0; j < 4; ++j) {
        int c = ty + j * 8;
        dst[base + (size_t)(c0 + c) * R + r0 + tx] = tile[tx][c];
    }
}

// ---------------- grouped GEMM: C[128,128] per block, bf16 MFMA 16x16x32 ----------------
// A: [slot][KTOT] bf16 (expert-sorted rows). B: [E][NTOT][KTOT] bf16 (pre-transposed).
// MODE 0: h = relu(A*B^T) -> bf16, rows = global slot. MODE 1: out = prob*(A*B^T) -> fp32, rows = token.
template<int KTOT, int NTOT, int MODE>
__global__ __launch_bounds__(256) void moe_gemm(
    const ushort_t* __restrict__ Aall, const ushort_t* __restrict__ Ball,
    const int* __restrict__ counts, const int* __restrict__ offsets,
    const int* __restrict__ perm, const float* __restrict__ topp,
    void* __restrict__ Cout)
{
    int e    = blockIdx.x >> 7;          // MAXT = 128
    int tile = blockIdx.x & (MAXT - 1);
    int count = counts[e];
    if (tile * 128 >= count) return;
    int n0   = blockIdx.y * 128;
    int goff = offsets[e] + tile * 128;

    const ushort_t* Ap = Aall + (size_t)goff * KTOT;
    const ushort_t* Bp = Ball + (size_t)e * KTOT * NTOT + (size_t)n0 * KTOT;

    __shared__ ushort_t As[128 * 64];
    __shared__ ushort_t Bs[128 * 64];
    __shared__ int   tokLds[128];
    __shared__ float probLds[128];

    int tid = threadIdx.x, lane = tid & 63, wave = tid >> 6;

    if (MODE == 1 && tid < 128) {
        int slot = tile * 128 + tid;
        int tok = (slot < count) ? perm[e * T + slot] : 0;
        tokLds[tid]  = tok;
        probLds[tid] = (slot < count) ? topp[tok] : 0.f;
    }

    f32x4 acc[4][4];
    const f32x4 zero = {0.f, 0.f, 0.f, 0.f};
#pragma unroll
    for (int mi = 0; mi < 4; ++mi)
#pragma unroll
        for (int ni = 0; ni < 4; ++ni) acc[mi][ni] = zero;

    int lrow = lane >> 3;               // staging: row within 8-row block
    int lk8  = (lane & 7) * 8;          // staging: 8-half (16 B) k chunk
    int wm   = (wave >> 1) * 64;
    int wn   = (wave & 1) * 64;
    int lm   = lane & 15;
    int q8   = (lane >> 4) * 8;

    for (int k0 = 0; k0 < KTOT; k0 += 64) {
#pragma unroll
        for (int it = 0; it < 4; ++it) {
            int rb  = wave * 4 + it;    // rowblock 0..15 (8 rows each)
            int row = rb * 8 + lrow;
            const ushort_t* ga = Ap + (size_t)row * KTOT + k0 + lk8;
            const ushort_t* gb = Bp + (size_t)row * KTOT + k0 + lk8;
            __builtin_amdgcn_global_load_lds(
                (const __attribute__((address_space(1))) unsigned int*)ga,
                (__attribute__((address_space(3))) unsigned int*)&As[rb * 512], 16, 0, 0);
            __builtin_amdgcn_global_load_lds(
                (const __attribute__((address_space(1))) unsigned int*)gb,
                (__attribute__((address_space(3))) unsigned int*)&Bs[rb * 512], 16, 0, 0);
        }
        __syncthreads();
#pragma unroll
        for (int kc = 0; kc < 64; kc += 32) {
            bf16x8 af[4], bb[4];
#pragma unroll
            for (int mi = 0; mi < 4; ++mi)
                af[mi] = *(const bf16x8*)&As[(wm + mi * 16 + lm) * 64 + kc + q8];
#pragma unroll
            for (int ni = 0; ni < 4; ++ni)
                bb[ni] = *(const bf16x8*)&Bs[(wn + ni * 16 + lm) * 64 + kc + q8];
#pragma unroll
            for (int mi = 0; mi < 4; ++mi)
#pragma unroll
                for (int ni = 0; ni < 4; ++ni)
                    acc[mi][ni] = __builtin_amdgcn_mfma_f32_16x16x32_bf16(
                        af[mi], bb[ni], acc[mi][ni], 0, 0, 0);
        }
        __syncthreads();
    }

    // epilogue: C layout col = lane&15, row = (lane>>4)*4 + reg
    int cr = (lane >> 4) * 4;
    int cc = lane & 15;
#pragma unroll
    for (int mi = 0; mi < 4; ++mi) {
#pragma unroll
        for (int r = 0; r < 4; ++r) {
            int m = wm + mi * 16 + cr + r;
            if (tile * 128 + m < count) {
                if (MODE == 0) {
                    ushort_t* hp = (ushort_t*)Cout + (size_t)(goff + m) * NTOT + n0 + wn + cc;
#pragma unroll
                    for (int ni = 0; ni < 4; ++ni) {
                        float v = acc[mi][ni][r];
                        hp[ni * 16] = f2bf(v > 0.f ? v : 0.f);
                    }
                } else {
                    int tok = tokLds[m];
                    float p = probLds[m];
                    float* op = (float*)Cout + (size_t)tok * NTOT + n0 + wn + cc;
#pragma unroll
                    for (int ni = 0; ni < 4; ++ni) op[ni * 16] = acc[mi][ni][r] * p;
                }
            }
        }
    }
}

// ---------------- workspace layout ----------------
constexpr size_t OFF_COUNTS  = 0;
constexpr size_t OFF_OFFSETS = 256;
constexpr size_t OFF_TOPP    = 512;
constexpr size_t OFF_PERM    = OFF_TOPP + (size_t)T * 4;                 // 66048
constexpr size_t OFF_XG      = OFF_PERM + (size_t)Eh * T * 4;            // 590336
constexpr size_t OFF_H       = OFF_XG + (size_t)(T + 128) * Dh * 2;      // 25,952,768
constexpr size_t OFF_WIN     = OFF_H + (size_t)(T + 128) * Fh * 2;       // 127,402,496
constexpr size_t OFF_WOUT    = OFF_WIN + (size_t)Eh * Dh * Fh * 2;       // 165,151,232
// total ws need = OFF_WOUT + Eh*Dh*Fh*2 = 202,899,968 bytes (~194 MiB)

extern "C" void kernel_launch(void* const* d_in, const int* in_sizes, int n_in,
                              void* d_out, int out_size, void* d_ws, size_t ws_size,
                              hipStream_t stream) {
    const float* x    = (const float*)d_in[0];   // [T, Dh]
    const float* rw   = (const float*)d_in[1];   // [Dh, Eh]
    const float* w_in = (const float*)d_in[2];   // [Eh, Dh, Fh]
    const float* w_out= (const float*)d_in[3];   // [Eh, Fh, Dh]

    float* out    = (float*)d_out;               // [T, Dh]
    float* logits = out + (size_t)T * Dh;        // [T, Eh]
    float* eidx   = logits + (size_t)T * Eh;     // [T] (stored as float)

    char* ws = (char*)d_ws;
    int*      counts  = (int*)(ws + OFF_COUNTS);
    int*      offsets = (int*)(ws + OFF_OFFSETS);
    float*    topp    = (float*)(ws + OFF_TOPP);
    int*      perm    = (int*)(ws + OFF_PERM);
    ushort_t* Xg      = (ushort_t*)(ws + OFF_XG);
    ushort_t* h       = (ushort_t*)(ws + OFF_H);
    ushort_t* WinT    = (ushort_t*)(ws + OFF_WIN);   // [E][Fh][Dh]
    ushort_t* WoutT   = (ushort_t*)(ws + OFF_WOUT);  // [E][Dh][Fh]

    init_counts<<<1, 64, 0, stream>>>(counts);
    router_kernel<<<T / 4, 256, 0, stream>>>(x, rw, logits, eidx, topp, counts, perm);
    scan_counts<<<1, 64, 0, stream>>>(counts, offsets);
    gather_cast_x<<<(T * (Dh / 4)) / 256, 256, 0, stream>>>(x, offsets, perm, Xg);
    transpose_cvt<<<dim3(Fh / 32, Dh / 32, Eh), dim3(32, 8), 0, stream>>>(w_in, WinT, Dh, Fh);
    transpose_cvt<<<dim3(Dh / 32, Fh / 32, Eh), dim3(32, 8), 0, stream>>>(w_out, WoutT, Fh, Dh);
    moe_gemm<Dh, Fh, 0><<<dim3(Eh * MAXT, Fh / 128), 256, 0, stream>>>(
        Xg, WinT, counts, offsets, perm, topp, (void*)h);
    moe_gemm<Fh, Dh, 1><<<dim3(Eh * MAXT, Dh / 128), 256, 0, stream>>>(
        h, WoutT, counts, offsets, perm, topp, (void*)out);
}

// Round 2
// 711.766 us; speedup vs baseline: 1.2818x; 1.2818x over previous
//
#include <hip/hip_runtime.h>
#include <hip/hip_bf16.h>

// ---------------- problem constants ----------------
constexpr int T  = 16384;   // B*S tokens
constexpr int Dh = 768;
constexpr int Fh = 3072;
constexpr int Eh = 8;
constexpr int MAXTILES = 136;  // sum ceil(count_e/128) <= T/128 + Eh = 136

typedef unsigned short ushort_t;
typedef __attribute__((ext_vector_type(8))) short  bf16x8;  // 8 bf16 = 4 VGPRs
typedef __attribute__((ext_vector_type(4))) float  f32x4;

// fp32 -> bf16 round-to-nearest-even (finite inputs)
static __device__ __forceinline__ ushort_t f2bf(float f) {
    unsigned u = __builtin_bit_cast(unsigned, f);
    u += 0x7FFFu + ((u >> 16) & 1u);
    return (ushort_t)(u >> 16);
}

// ---------------- init: zero the expert counters ----------------
__global__ void init_counts(int* counts) {
    if (threadIdx.x < Eh) counts[threadIdx.x] = 0;
}

// ---------------- router: one wave per token ----------------
// fp64 accumulation so argmax matches the reference in practice.
__global__ void router_kernel(const float* __restrict__ x, const float* __restrict__ rw,
                              float* __restrict__ logits_out, float* __restrict__ eidx_out,
                              float* __restrict__ topp, int* __restrict__ counts,
                              int* __restrict__ perm) {
    int gt   = blockIdx.x * 256 + threadIdx.x;
    int t    = gt >> 6;
    int lane = threadIdx.x & 63;
    const float* xr = x + (size_t)t * Dh;

    double acc[Eh];
#pragma unroll
    for (int e = 0; e < Eh; ++e) acc[e] = 0.0;

#pragma unroll
    for (int j = 0; j < Dh / 64; ++j) {
        int d = lane + j * 64;
        float xv = xr[d];
        const float* rwr = rw + d * Eh;
#pragma unroll
        for (int e = 0; e < Eh; ++e) acc[e] += (double)xv * (double)rwr[e];
    }
#pragma unroll
    for (int off = 32; off > 0; off >>= 1) {
#pragma unroll
        for (int e = 0; e < Eh; ++e) acc[e] += __shfl_xor(acc[e], off, 64);
    }
    if (lane == 0) {
        float l32[Eh];
        float m = -3.4e38f; int amax = 0;
#pragma unroll
        for (int e = 0; e < Eh; ++e) l32[e] = (float)acc[e];
#pragma unroll
        for (int e = 0; e < Eh; ++e) {
            if (l32[e] > m) { m = l32[e]; amax = e; }  // strict > : first max wins (np.argmax)
        }
        float s = 0.f;
#pragma unroll
        for (int e = 0; e < Eh; ++e) s += expf(l32[e] - m);
#pragma unroll
        for (int e = 0; e < Eh; ++e) logits_out[(size_t)t * Eh + e] = l32[e];
        eidx_out[t] = (float)amax;
        topp[t]     = 1.0f / s;   // softmax prob of the max logit
        int slot = atomicAdd(&counts[amax], 1);
        perm[amax * T + slot] = t;
    }
}

// ---------------- scan counts + build compact tile work list ----------------
__global__ void scan_counts(const int* counts, int* offsets,
                            int* tE, int* tGoff, int* tSlot0, int* tRows, int* nT) {
    if (threadIdx.x == 0) {
        int off = 0, n = 0;
        for (int e = 0; e < Eh; ++e) {
            offsets[e] = off;
            int c = counts[e];
            for (int t0 = 0; t0 < c; t0 += 128) {
                tE[n] = e; tGoff[n] = off + t0; tSlot0[n] = t0;
                tRows[n] = (c - t0 < 128) ? (c - t0) : 128;
                ++n;
            }
            off += c;
        }
        offsets[Eh] = off;
        nT[0] = n;
    }
}

// ---------------- gather tokens into expert-sorted bf16 rows ----------------
__global__ void gather_cast_x(const float* __restrict__ x, const int* __restrict__ offsets,
                              const int* __restrict__ perm, ushort_t* __restrict__ Xg) {
    __shared__ int soff[Eh + 1];
    if (threadIdx.x < Eh + 1) soff[threadIdx.x] = offsets[threadIdx.x];
    __syncthreads();
    int q  = blockIdx.x * 256 + threadIdx.x;     // float4 index, exact grid
    int g  = q / (Dh / 4);
    int cq = (q - g * (Dh / 4)) * 4;
    int e = 0;
#pragma unroll
    for (int i = 1; i < Eh; ++i) e += (g >= soff[i]);
    int tok = perm[e * T + (g - soff[e])];
    const float4 v = *(const float4*)(x + (size_t)tok * Dh + cq);
    ushort4 o;
    o.x = f2bf(v.x); o.y = f2bf(v.y); o.z = f2bf(v.z); o.w = f2bf(v.w);
    *(ushort4*)(Xg + (size_t)g * Dh + cq) = o;
}

// ---------------- transpose + cast weights: src[R][C] fp32 -> dst[C][R] bf16 ----------------
__global__ void transpose_cvt(const float* __restrict__ src, ushort_t* __restrict__ dst,
                              int R, int C) {
    __shared__ ushort_t tile[32][33];
    int tx = threadIdx.x, ty = threadIdx.y;      // block (32, 8)
    size_t base = (size_t)blockIdx.z * (size_t)R * (size_t)C;
    int c0 = blockIdx.x * 32, r0 = blockIdx.y * 32;
#pragma unroll
    for (int j = 0; j < 4; ++j) {
        int r = ty + j * 8;
        tile[r][tx] = f2bf(src[base + (size_t)(r0 + r) * C + c0 + tx]);
    }
    __syncthreads();
    int idx = ty * 32 + tx;
#pragma unroll
    for (int j = 0; j < 2; ++j) {
        int lin = idx + j * 256;
        int c  = lin >> 4;          // 0..31 output row (src col)
        int rp = (lin & 15) * 2;    // pair of src rows
        ushort2 o = { tile[rp][c], tile[rp + 1][c] };
        *(ushort2*)(dst + base + (size_t)(c0 + c) * R + r0 + rp) = o;
    }
}

// ---------------- grouped GEMM: C[128,128] per block, bf16 MFMA 16x16x32 ----------------
// A: [slot][KTOT] bf16 (expert-sorted rows, padded +128 rows). B: [E][NTOT][KTOT] bf16.
// LDS tiles use an XOR bank swizzle: row r's 16-B chunk g lives at position g ^ (r&7).
// MODE 0: h = relu(A*B^T) -> bf16, rows = global slot. MODE 1: out = prob*(A*B^T) -> fp32, rows = token.
template<int KTOT, int NTOT, int MODE>
__global__ __launch_bounds__(256) void moe_gemm(
    const ushort_t* __restrict__ Aall, const ushort_t* __restrict__ Ball,
    const int* __restrict__ tE, const int* __restrict__ tGoff,
    const int* __restrict__ tSlot0, const int* __restrict__ tRows,
    const int* __restrict__ nT,
    const int* __restrict__ perm, const float* __restrict__ topp,
    void* __restrict__ Cout)
{
    int i = blockIdx.x;
    if (i >= nT[0]) return;
    int e     = tE[i];
    int goff  = tGoff[i];
    int slot0 = tSlot0[i];
    int rows  = tRows[i];
    int n0    = blockIdx.y * 128;

    const ushort_t* Ap = Aall + (size_t)goff * KTOT;
    const ushort_t* Bp = Ball + (size_t)e * KTOT * NTOT + (size_t)n0 * KTOT;

    __shared__ ushort_t As[128 * 64];
    __shared__ ushort_t Bs[128 * 64];
    __shared__ int   tokLds[128];
    __shared__ float probLds[128];

    int tid = threadIdx.x, lane = tid & 63, wave = tid >> 6;

    if (MODE == 1 && tid < 128) {
        int tok = (tid < rows) ? perm[e * T + slot0 + tid] : 0;
        tokLds[tid]  = tok;
        probLds[tid] = (tid < rows) ? topp[tok] : 0.f;
    }

    f32x4 acc[4][4];
    const f32x4 zero = {0.f, 0.f, 0.f, 0.f};
#pragma unroll
    for (int mi = 0; mi < 4; ++mi)
#pragma unroll
        for (int ni = 0; ni < 4; ++ni) acc[mi][ni] = zero;

    // staging: lane covers row (lane>>3) within 8-row block, chunk position (lane&7).
    // Source chunk is XOR-swizzled: gsrc = (lane&7) ^ (lane>>3).
    int lrow  = lane >> 3;
    int gsrc8 = ((lane & 7) ^ lrow) * 8;        // swizzled source offset in halves
    int wm    = (wave >> 1) * 64;
    int wn    = (wave & 1) * 64;
    int lm    = lane & 15;
    int lm7   = lm & 7;
    int gq    = lane >> 4;                       // fragment chunk base (0..3)

    for (int k0 = 0; k0 < KTOT; k0 += 64) {
#pragma unroll
        for (int it = 0; it < 4; ++it) {
            int rb  = wave * 4 + it;            // rowblock 0..15 (8 rows each)
            int row = rb * 8 + lrow;
            const ushort_t* ga = Ap + (size_t)row * KTOT + k0 + gsrc8;
            const ushort_t* gb = Bp + (size_t)row * KTOT + k0 + gsrc8;
            __builtin_amdgcn_global_load_lds(
                (const __attribute__((address_space(1))) unsigned int*)ga,
                (__attribute__((address_space(3))) unsigned int*)&As[rb * 512], 16, 0, 0);
            __builtin_amdgcn_global_load_lds(
                (const __attribute__((address_space(1))) unsigned int*)gb,
                (__attribute__((address_space(3))) unsigned int*)&Bs[rb * 512], 16, 0, 0);
        }
        __syncthreads();
#pragma unroll
        for (int kc = 0; kc < 64; kc += 32) {
            int cbase = gq + (kc >> 3);          // fragment chunk index (0..7)
            bf16x8 af[4], bb[4];
#pragma unroll
            for (int mi = 0; mi < 4; ++mi) {
                int row = wm + mi * 16 + lm;     // row&7 == lm7
                af[mi] = *(const bf16x8*)&As[row * 64 + ((cbase ^ lm7) * 8)];
            }
#pragma unroll
            for (int ni = 0; ni < 4; ++ni) {
                int row = wn + ni * 16 + lm;
                bb[ni] = *(const bf16x8*)&Bs[row * 64 + ((cbase ^ lm7) * 8)];
            }
#pragma unroll
            for (int mi = 0; mi < 4; ++mi)
#pragma unroll
                for (int ni = 0; ni < 4; ++ni)
                    acc[mi][ni] = __builtin_amdgcn_mfma_f32_16x16x32_bf16(
                        af[mi], bb[ni], acc[mi][ni], 0, 0, 0);
        }
        __syncthreads();
    }

    // epilogue: C layout col = lane&15, row = (lane>>4)*4 + reg
    int cr = (lane >> 4) * 4;
    int cc = lane & 15;
#pragma unroll
    for (int mi = 0; mi < 4; ++mi) {
#pragma unroll
        for (int r = 0; r < 4; ++r) {
            int m = wm + mi * 16 + cr + r;
            if (m < rows) {
                if (MODE == 0) {
                    ushort_t* hp = (ushort_t*)Cout + (size_t)(goff + m) * NTOT + n0 + wn + cc;
#pragma unroll
                    for (int ni = 0; ni < 4; ++ni) {
                        float v = acc[mi][ni][r];
                        hp[ni * 16] = f2bf(v > 0.f ? v : 0.f);
                    }
                } else {
                    int tok = tokLds[m];
                    float p = probLds[m];
                    float* op = (float*)Cout + (size_t)tok * NTOT + n0 + wn + cc;
#pragma unroll
                    for (int ni = 0; ni < 4; ++ni) op[ni * 16] = acc[mi][ni][r] * p;
                }
            }
        }
    }
}

// ---------------- workspace layout ----------------
constexpr size_t OFF_COUNTS  = 0;
constexpr size_t OFF_OFFSETS = 256;
constexpr size_t OFF_TILES   = 512;                                      // 5 arrays of 144 ints + nT
constexpr size_t OFF_TOPP    = OFF_TILES + 4 * 144 * 5 + 64;             // a bit of slack
constexpr size_t OFF_PERM    = OFF_TOPP + (size_t)T * 4;
constexpr size_t OFF_XG      = (OFF_PERM + (size_t)Eh * T * 4 + 255) & ~(size_t)255;
constexpr size_t OFF_H       = (OFF_XG + (size_t)(T + 128) * Dh * 2 + 255) & ~(size_t)255;
constexpr size_t OFF_WIN     = (OFF_H + (size_t)(T + 128) * Fh * 2 + 255) & ~(size_t)255;
constexpr size_t OFF_WOUT    = (OFF_WIN + (size_t)Eh * Dh * Fh * 2 + 255) & ~(size_t)255;
// total ws need ~ 203 MB

extern "C" void kernel_launch(void* const* d_in, const int* in_sizes, int n_in,
                              void* d_out, int out_size, void* d_ws, size_t ws_size,
                              hipStream_t stream) {
    const float* x    = (const float*)d_in[0];   // [T, Dh]
    const float* rw   = (const float*)d_in[1];   // [Dh, Eh]
    const float* w_in = (const float*)d_in[2];   // [Eh, Dh, Fh]
    const float* w_out= (const float*)d_in[3];   // [Eh, Fh, Dh]

    float* out    = (float*)d_out;               // [T, Dh]
    float* logits = out + (size_t)T * Dh;        // [T, Eh]
    float* eidx   = logits + (size_t)T * Eh;     // [T] (stored as float)

    char* ws = (char*)d_ws;
    int*      counts  = (int*)(ws + OFF_COUNTS);
    int*      offsets = (int*)(ws + OFF_OFFSETS);
    int*      tE      = (int*)(ws + OFF_TILES);
    int*      tGoff   = tE + 144;
    int*      tSlot0  = tGoff + 144;
    int*      tRows   = tSlot0 + 144;
    int*      nT      = tRows + 144;
    float*    topp    = (float*)(ws + OFF_TOPP);
    int*      perm    = (int*)(ws + OFF_PERM);
    ushort_t* Xg      = (ushort_t*)(ws + OFF_XG);
    ushort_t* h       = (ushort_t*)(ws + OFF_H);
    ushort_t* WinT    = (ushort_t*)(ws + OFF_WIN);   // [E][Fh][Dh]
    ushort_t* WoutT   = (ushort_t*)(ws + OFF_WOUT);  // [E][Dh][Fh]

    init_counts<<<1, 64, 0, stream>>>(counts);
    router_kernel<<<T / 4, 256, 0, stream>>>(x, rw, logits, eidx, topp, counts, perm);
    scan_counts<<<1, 64, 0, stream>>>(counts, offsets, tE, tGoff, tSlot0, tRows, nT);
    gather_cast_x<<<(T * (Dh / 4)) / 256, 256, 0, stream>>>(x, offsets, perm, Xg);
    transpose_cvt<<<dim3(Fh / 32, Dh / 32, Eh), dim3(32, 8), 0, stream>>>(w_in, WinT, Dh, Fh);
    transpose_cvt<<<dim3(Dh / 32, Fh / 32, Eh), dim3(32, 8), 0, stream>>>(w_out, WoutT, Fh, Dh);
    moe_gemm<Dh, Fh, 0><<<dim3(MAXTILES, Fh / 128), 256, 0, stream>>>(
        Xg, WinT, tE, tGoff, tSlot0, tRows, nT, perm, topp, (void*)h);
    moe_gemm<Fh, Dh, 1><<<dim3(MAXTILES, Dh / 128), 256, 0, stream>>>(
        h, WoutT, tE, tGoff, tSlot0, tRows, nT, perm, topp, (void*)out);
}

// Round 3
// 554.026 us; speedup vs baseline: 1.6468x; 1.2847x over previous
//
#include <hip/hip_runtime.h>
#include <hip/hip_bf16.h>

// ---------------- problem constants ----------------
constexpr int T  = 16384;   // B*S tokens
constexpr int Dh = 768;
constexpr int Fh = 3072;
constexpr int Eh = 8;
constexpr int MAXTILES = 136;  // sum ceil(count_e/128) <= T/128 + Eh = 136

typedef unsigned short ushort_t;
typedef __attribute__((ext_vector_type(8))) short  bf16x8;  // 8 bf16 = 4 VGPRs
typedef __attribute__((ext_vector_type(4))) float  f32x4;

// fp32 -> bf16 round-to-nearest-even (finite inputs)
static __device__ __forceinline__ ushort_t f2bf(float f) {
    unsigned u = __builtin_bit_cast(unsigned, f);
    u += 0x7FFFu + ((u >> 16) & 1u);
    return (ushort_t)(u >> 16);
}

// ---------------- init: zero the expert counters ----------------
__global__ void init_counts(int* counts) {
    if (threadIdx.x < Eh) counts[threadIdx.x] = 0;
}

// ---------------- router v2: 16 tokens per 1024-thread block ----------------
// rw staged transposed in LDS; fp64 accumulation (argmax must match np exactly);
// block-aggregated atomics for the expert counters.
__global__ __launch_bounds__(1024) void router_kernel(
    const float* __restrict__ x, const float* __restrict__ rw,
    float* __restrict__ logits_out, float* __restrict__ eidx_out,
    float* __restrict__ topp, int* __restrict__ counts, int* __restrict__ perm) {

    __shared__ float rwT[Eh][Dh];   // 24 KB, transposed router weights
    __shared__ int   sAmax[16];
    __shared__ int   sBase[Eh];

    int tid = threadIdx.x;
    // stage rw [Dh][Eh] -> rwT[e][d]; global read coalesced
    for (int i = tid; i < Dh * Eh; i += 1024) {
        int d = i >> 3, e = i & 7;
        rwT[e][d] = rw[i];
    }
    __syncthreads();

    int wave = tid >> 6, lane = tid & 63;
    int t = blockIdx.x * 16 + wave;
    const float* xr = x + (size_t)t * Dh;

    double acc[Eh];
#pragma unroll
    for (int e = 0; e < Eh; ++e) acc[e] = 0.0;

#pragma unroll
    for (int j = 0; j < Dh / 256; ++j) {
        int d = lane * 4 + j * 256;
        const float4 xv = *(const float4*)(xr + d);
#pragma unroll
        for (int e = 0; e < Eh; ++e) {
            const float4 w = *(const float4*)&rwT[e][d];
            acc[e] += (double)xv.x * (double)w.x + (double)xv.y * (double)w.y
                    + (double)xv.z * (double)w.z + (double)xv.w * (double)w.w;
        }
    }
#pragma unroll
    for (int off = 32; off > 0; off >>= 1) {
#pragma unroll
        for (int e = 0; e < Eh; ++e) acc[e] += __shfl_xor(acc[e], off, 64);
    }

    int amax = 0;
    if (lane == 0) {
        float l32[Eh];
        float m = -3.4e38f;
#pragma unroll
        for (int e = 0; e < Eh; ++e) l32[e] = (float)acc[e];
#pragma unroll
        for (int e = 0; e < Eh; ++e) {
            if (l32[e] > m) { m = l32[e]; amax = e; }  // strict > : first max wins (np.argmax)
        }
        float s = 0.f;
#pragma unroll
        for (int e = 0; e < Eh; ++e) s += expf(l32[e] - m);
#pragma unroll
        for (int e = 0; e < Eh; ++e) logits_out[(size_t)t * Eh + e] = l32[e];
        eidx_out[t] = (float)amax;
        topp[t]     = 1.0f / s;   // softmax prob of the max logit
        sAmax[wave] = amax;
    }
    __syncthreads();

    if (tid < Eh) {
        int c = 0;
#pragma unroll
        for (int w = 0; w < 16; ++w) c += (sAmax[w] == tid);
        sBase[tid] = (c > 0) ? atomicAdd(&counts[tid], c) : 0;
    }
    __syncthreads();

    if (lane == 0) {
        int prior = 0;
        for (int w = 0; w < wave; ++w) prior += (sAmax[w] == amax);
        perm[amax * T + sBase[amax] + prior] = t;
    }
}

// ---------------- scan counts + build compact tile work list ----------------
__global__ void scan_counts(const int* counts, int* offsets,
                            int* tE, int* tGoff, int* tSlot0, int* tRows, int* nT) {
    if (threadIdx.x == 0) {
        int off = 0, n = 0;
        for (int e = 0; e < Eh; ++e) {
            offsets[e] = off;
            int c = counts[e];
            for (int t0 = 0; t0 < c; t0 += 128) {
                tE[n] = e; tGoff[n] = off + t0; tSlot0[n] = t0;
                tRows[n] = (c - t0 < 128) ? (c - t0) : 128;
                ++n;
            }
            off += c;
        }
        offsets[Eh] = off;
        nT[0] = n;
    }
}

// ---------------- gather tokens into expert-sorted bf16 rows ----------------
__global__ void gather_cast_x(const float* __restrict__ x, const int* __restrict__ offsets,
                              const int* __restrict__ perm, ushort_t* __restrict__ Xg) {
    __shared__ int soff[Eh + 1];
    if (threadIdx.x < Eh + 1) soff[threadIdx.x] = offsets[threadIdx.x];
    __syncthreads();
    int q  = blockIdx.x * 256 + threadIdx.x;     // float4 index, exact grid
    int g  = q / (Dh / 4);
    int cq = (q - g * (Dh / 4)) * 4;
    int e = 0;
#pragma unroll
    for (int i = 1; i < Eh; ++i) e += (g >= soff[i]);
    int tok = perm[e * T + (g - soff[e])];
    const float4 v = *(const float4*)(x + (size_t)tok * Dh + cq);
    ushort4 o;
    o.x = f2bf(v.x); o.y = f2bf(v.y); o.z = f2bf(v.z); o.w = f2bf(v.w);
    *(ushort4*)(Xg + (size_t)g * Dh + cq) = o;
}

// ---------------- transpose + cast weights: src[R][C] fp32 -> dst[C][R] bf16 ----------------
__global__ void transpose_cvt(const float* __restrict__ src, ushort_t* __restrict__ dst,
                              int R, int C) {
    __shared__ ushort_t tile[32][33];
    int tx = threadIdx.x, ty = threadIdx.y;      // block (32, 8)
    size_t base = (size_t)blockIdx.z * (size_t)R * (size_t)C;
    int c0 = blockIdx.x * 32, r0 = blockIdx.y * 32;
#pragma unroll
    for (int j = 0; j < 4; ++j) {
        int r = ty + j * 8;
        tile[r][tx] = f2bf(src[base + (size_t)(r0 + r) * C + c0 + tx]);
    }
    __syncthreads();
    int idx = ty * 32 + tx;
#pragma unroll
    for (int j = 0; j < 2; ++j) {
        int lin = idx + j * 256;
        int c  = lin >> 4;          // 0..31 output row (src col)
        int rp = (lin & 15) * 2;    // pair of src rows
        ushort2 o = { tile[rp][c], tile[rp + 1][c] };
        *(ushort2*)(dst + base + (size_t)(c0 + c) * R + r0 + rp) = o;
    }
}

// ---------------- grouped GEMM: C[128,128] per block, bf16 MFMA 16x16x32 ----------------
// A: [slot][KTOT] bf16 (expert-sorted rows, padded +128 rows). B: [E][NTOT][KTOT] bf16.
// LDS tiles use an XOR bank swizzle: row r's 16-B chunk g lives at position g ^ (r&7).
// MODE 0: h = relu(A*B^T) -> bf16, rows = global slot. MODE 1: out = prob*(A*B^T) -> fp32, rows = token.
template<int KTOT, int NTOT, int MODE>
__global__ __launch_bounds__(256) void moe_gemm(
    const ushort_t* __restrict__ Aall, const ushort_t* __restrict__ Ball,
    const int* __restrict__ tE, const int* __restrict__ tGoff,
    const int* __restrict__ tSlot0, const int* __restrict__ tRows,
    const int* __restrict__ nT,
    const int* __restrict__ perm, const float* __restrict__ topp,
    void* __restrict__ Cout)
{
    int i = blockIdx.x;
    if (i >= nT[0]) return;
    int e     = tE[i];
    int goff  = tGoff[i];
    int slot0 = tSlot0[i];
    int rows  = tRows[i];
    int n0    = blockIdx.y * 128;

    const ushort_t* Ap = Aall + (size_t)goff * KTOT;
    const ushort_t* Bp = Ball + (size_t)e * KTOT * NTOT + (size_t)n0 * KTOT;

    __shared__ ushort_t As[128 * 64];
    __shared__ ushort_t Bs[128 * 64];
    __shared__ int   tokLds[128];
    __shared__ float probLds[128];

    int tid = threadIdx.x, lane = tid & 63, wave = tid >> 6;

    if (MODE == 1 && tid < 128) {
        int tok = (tid < rows) ? perm[e * T + slot0 + tid] : 0;
        tokLds[tid]  = tok;
        probLds[tid] = (tid < rows) ? topp[tok] : 0.f;
    }

    f32x4 acc[4][4];
    const f32x4 zero = {0.f, 0.f, 0.f, 0.f};
#pragma unroll
    for (int mi = 0; mi < 4; ++mi)
#pragma unroll
        for (int ni = 0; ni < 4; ++ni) acc[mi][ni] = zero;

    // staging: lane covers row (lane>>3) within 8-row block, chunk position (lane&7).
    // Source chunk is XOR-swizzled: gsrc = (lane&7) ^ (lane>>3).
    int lrow  = lane >> 3;
    int gsrc8 = ((lane & 7) ^ lrow) * 8;        // swizzled source offset in halves
    int wm    = (wave >> 1) * 64;
    int wn    = (wave & 1) * 64;
    int lm    = lane & 15;
    int lm7   = lm & 7;
    int gq    = lane >> 4;                       // fragment chunk base (0..3)

    for (int k0 = 0; k0 < KTOT; k0 += 64) {
#pragma unroll
        for (int it = 0; it < 4; ++it) {
            int rb  = wave * 4 + it;            // rowblock 0..15 (8 rows each)
            int row = rb * 8 + lrow;
            const ushort_t* ga = Ap + (size_t)row * KTOT + k0 + gsrc8;
            const ushort_t* gb = Bp + (size_t)row * KTOT + k0 + gsrc8;
            __builtin_amdgcn_global_load_lds(
                (const __attribute__((address_space(1))) unsigned int*)ga,
                (__attribute__((address_space(3))) unsigned int*)&As[rb * 512], 16, 0, 0);
            __builtin_amdgcn_global_load_lds(
                (const __attribute__((address_space(1))) unsigned int*)gb,
                (__attribute__((address_space(3))) unsigned int*)&Bs[rb * 512], 16, 0, 0);
        }
        __syncthreads();
#pragma unroll
        for (int kc = 0; kc < 64; kc += 32) {
            int cbase = gq + (kc >> 3);          // fragment chunk index (0..7)
            bf16x8 af[4], bb[4];
#pragma unroll
            for (int mi = 0; mi < 4; ++mi) {
                int row = wm + mi * 16 + lm;     // row&7 == lm7
                af[mi] = *(const bf16x8*)&As[row * 64 + ((cbase ^ lm7) * 8)];
            }
#pragma unroll
            for (int ni = 0; ni < 4; ++ni) {
                int row = wn + ni * 16 + lm;
                bb[ni] = *(const bf16x8*)&Bs[row * 64 + ((cbase ^ lm7) * 8)];
            }
#pragma unroll
            for (int mi = 0; mi < 4; ++mi)
#pragma unroll
                for (int ni = 0; ni < 4; ++ni)
                    acc[mi][ni] = __builtin_amdgcn_mfma_f32_16x16x32_bf16(
                        af[mi], bb[ni], acc[mi][ni], 0, 0, 0);
        }
        __syncthreads();
    }

    // epilogue: C layout col = lane&15, row = (lane>>4)*4 + reg
    int cr = (lane >> 4) * 4;
    int cc = lane & 15;
#pragma unroll
    for (int mi = 0; mi < 4; ++mi) {
#pragma unroll
        for (int r = 0; r < 4; ++r) {
            int m = wm + mi * 16 + cr + r;
            if (m < rows) {
                if (MODE == 0) {
                    ushort_t* hp = (ushort_t*)Cout + (size_t)(goff + m) * NTOT + n0 + wn + cc;
#pragma unroll
                    for (int ni = 0; ni < 4; ++ni) {
                        float v = acc[mi][ni][r];
                        hp[ni * 16] = f2bf(v > 0.f ? v : 0.f);
                    }
                } else {
                    int tok = tokLds[m];
                    float p = probLds[m];
                    float* op = (float*)Cout + (size_t)tok * NTOT + n0 + wn + cc;
#pragma unroll
                    for (int ni = 0; ni < 4; ++ni) op[ni * 16] = acc[mi][ni][r] * p;
                }
            }
        }
    }
}

// ---------------- workspace layout ----------------
constexpr size_t OFF_COUNTS  = 0;
constexpr size_t OFF_OFFSETS = 256;
constexpr size_t OFF_TILES   = 512;                                      // 5 arrays of 144 ints + nT
constexpr size_t OFF_TOPP    = OFF_TILES + 4 * 144 * 5 + 64;             // a bit of slack
constexpr size_t OFF_PERM    = OFF_TOPP + (size_t)T * 4;
constexpr size_t OFF_XG      = (OFF_PERM + (size_t)Eh * T * 4 + 255) & ~(size_t)255;
constexpr size_t OFF_H       = (OFF_XG + (size_t)(T + 128) * Dh * 2 + 255) & ~(size_t)255;
constexpr size_t OFF_WIN     = (OFF_H + (size_t)(T + 128) * Fh * 2 + 255) & ~(size_t)255;
constexpr size_t OFF_WOUT    = (OFF_WIN + (size_t)Eh * Dh * Fh * 2 + 255) & ~(size_t)255;
// total ws need ~ 203 MB

extern "C" void kernel_launch(void* const* d_in, const int* in_sizes, int n_in,
                              void* d_out, int out_size, void* d_ws, size_t ws_size,
                              hipStream_t stream) {
    const float* x    = (const float*)d_in[0];   // [T, Dh]
    const float* rw   = (const float*)d_in[1];   // [Dh, Eh]
    const float* w_in = (const float*)d_in[2];   // [Eh, Dh, Fh]
    const float* w_out= (const float*)d_in[3];   // [Eh, Fh, Dh]

    float* out    = (float*)d_out;               // [T, Dh]
    float* logits = out + (size_t)T * Dh;        // [T, Eh]
    float* eidx   = logits + (size_t)T * Eh;     // [T] (stored as float)

    char* ws = (char*)d_ws;
    int*      counts  = (int*)(ws + OFF_COUNTS);
    int*      offsets = (int*)(ws + OFF_OFFSETS);
    int*      tE      = (int*)(ws + OFF_TILES);
    int*      tGoff   = tE + 144;
    int*      tSlot0  = tGoff + 144;
    int*      tRows   = tSlot0 + 144;
    int*      nT      = tRows + 144;
    float*    topp    = (float*)(ws + OFF_TOPP);
    int*      perm    = (int*)(ws + OFF_PERM);
    ushort_t* Xg      = (ushort_t*)(ws + OFF_XG);
    ushort_t* h       = (ushort_t*)(ws + OFF_H);
    ushort_t* WinT    = (ushort_t*)(ws + OFF_WIN);   // [E][Fh][Dh]
    ushort_t* WoutT   = (ushort_t*)(ws + OFF_WOUT);  // [E][Dh][Fh]

    init_counts<<<1, 64, 0, stream>>>(counts);
    router_kernel<<<T / 16, 1024, 0, stream>>>(x, rw, logits, eidx, topp, counts, perm);
    scan_counts<<<1, 64, 0, stream>>>(counts, offsets, tE, tGoff, tSlot0, tRows, nT);
    gather_cast_x<<<(T * (Dh / 4)) / 256, 256, 0, stream>>>(x, offsets, perm, Xg);
    transpose_cvt<<<dim3(Fh / 32, Dh / 32, Eh), dim3(32, 8), 0, stream>>>(w_in, WinT, Dh, Fh);
    transpose_cvt<<<dim3(Dh / 32, Fh / 32, Eh), dim3(32, 8), 0, stream>>>(w_out, WoutT, Fh, Dh);
    moe_gemm<Dh, Fh, 0><<<dim3(MAXTILES, Fh / 128), 256, 0, stream>>>(
        Xg, WinT, tE, tGoff, tSlot0, tRows, nT, perm, topp, (void*)h);
    moe_gemm<Fh, Dh, 1><<<dim3(MAXTILES, Dh / 128), 256, 0, stream>>>(
        h, WoutT, tE, tGoff, tSlot0, tRows, nT, perm, topp, (void*)out);
}